// Round 12
// baseline (10431.297 us; speedup 1.0000x reference)
//
#include <hip/hip_runtime.h>

#define B_ 128
#define T_ 2048
#define H_ 128
#define IN_ 6
#define GRP_ 8                  // steps per inner group
#define NGRP_ (T_ / GRP_)       // 256
#define CHUNK_ 32               // steps per flag chunk
#define NCHUNK_ (T_ / CHUNK_)   // 64
#define FLAG_STRIDE_ 64         // uints between flags (256B)
#define HS_ 144                 // LDS row stride in shorts
#define XGRING_ 2               // xg ring depth (chunks) — R19-proven protocol
#define XGSLOT_ (CHUNK_ * 8192) // floats per ring slot (1 MiB)
#define NFLAGS_ 184  // fh[l][sl]=l*32+sl (l<2); fx[gl][bg]=64+gl*8+bg; fc[gl][sl]=88+gl*32+sl

typedef _Float16 f16x8 __attribute__((ext_vector_type(8)));
typedef float    f32x4 __attribute__((ext_vector_type(4)));

__device__ __forceinline__ unsigned short f2h_u(float f) {
  union { _Float16 h; unsigned short u; } v; v.h = (_Float16)f; return v.u;
}
__device__ __forceinline__ unsigned int pack2(float a, float b) {
  return (unsigned int)f2h_u(a) | ((unsigned int)f2h_u(b) << 16);
}
__device__ __forceinline__ float sigf_(float x) {
  return __builtin_amdgcn_rcpf(1.0f + __expf(-x));
}
__device__ __forceinline__ float tanhf_(float x) {
  return 2.0f * __builtin_amdgcn_rcpf(1.0f + __expf(-2.0f * x)) - 1.0f;
}
__device__ __forceinline__ f16x8 load_w8(const float* __restrict__ p) {
  f16x8 r;
#pragma unroll
  for (int i = 0; i < 8; ++i) r[i] = (_Float16)p[i];
  return r;
}

__global__ void init_flags(unsigned int* flags) {
  flags[blockIdx.x * 256 + threadIdx.x] = 0u;  // grid 46 -> 11776 = 184 * 64
}

// lgkm-only barrier: h-exchange visibility WITHOUT draining vmcnt.
#define BARRIER_LGKM()                                              \
  do {                                                              \
    asm volatile("s_waitcnt lgkmcnt(0)" ::: "memory");              \
    __builtin_amdgcn_s_barrier();                                   \
    __builtin_amdgcn_sched_barrier(0);                              \
  } while (0)

// vmcnt is PER-WAVE: before any flag publish, ALL waves drain, then barrier.
#define PUBLISH_FENCE()                                             \
  do {                                                              \
    asm volatile("s_waitcnt vmcnt(0)" ::: "memory");                \
    __builtin_amdgcn_s_barrier();                                   \
  } while (0)

#define MFMA16(A, B, C) __builtin_amdgcn_mfma_f32_16x16x32_f16((A), (B), (C), 0, 0, 0)

// ---------------------------------------------------------------------------
// R24: TWO full R16-style chains per 1024-thread WG (16 waves; waves 0-7 =
// slice 2p, waves 8-15 = slice 2p+1), sharing the ONE hardware s_barrier.
// Per SIMD: 4 waves (2 per chain). Window edges align, but within a window
// the chains are independent — chain B's MFMAs issue while chain A sits in
// its serial skeleton (ds_read latency / MFMA tail / act chain). Amortized
// target ~620-750 cy/step vs R16's measured 1806.
//  - Layer 0's x-GEMM offloaded to gl0 producers (R19-proven, bit-identical)
//    so all rec layers are uniform 16-MFMA/wave ring consumers.
//  - Fused pairs share bg -> fx wait stays a single shared tid0 WAITP (no
//    divergent barriers). Per-slice fh/fc publishes dualized (tid 0 / 512)
//    after the joint PUBLISH_FENCE.
//  - Producers: 24 WGs x 1024 thr; gate-split across wave halves (waves 0-7:
//    gates 0,1; waves 8-15: gates 2,3), staging guarded by tid<512.
//  - Rings depth-2, R19 flag protocol (ran correct twice). ws ~112 MB.
// ---------------------------------------------------------------------------
__global__ __launch_bounds__(1024, 4)
void lstm_pipe(const float* __restrict__ x,
               const float* __restrict__ Wih0, const float* __restrict__ Whh0,
               const float* __restrict__ bih0, const float* __restrict__ bhh0,
               const float* __restrict__ Wih1, const float* __restrict__ Whh1,
               const float* __restrict__ bih1, const float* __restrict__ bhh1,
               const float* __restrict__ Wih2, const float* __restrict__ Whh2,
               const float* __restrict__ bih2, const float* __restrict__ bhh2,
               unsigned short* __restrict__ region,   // f16 [B][T][128]
               float* __restrict__ xg,                // 24 rings [gl*8+bg][2][XGSLOT_]
               unsigned int* __restrict__ state_h,    // [B][64] f16x2
               unsigned int* __restrict__ flags)
{
  const int bid  = blockIdx.x;
  const int tid  = threadIdx.x;
  const int lane = tid & 63;
  const int wv   = tid >> 6;    // wave 0..15
  const int n16  = lane & 15;
  const int quad = lane >> 4;

  __shared__ unsigned short smem[32 * 16 * HS_];   // 147456 B (producer max)
  __shared__ int s_have;

#define WAITP(ptr_, need_, have_)                                   \
  do {                                                              \
    if ((have_) < (need_)) {                                        \
      if (tid == 0) {                                               \
        int v = (int)__hip_atomic_load(ptr_, __ATOMIC_RELAXED,      \
                                       __HIP_MEMORY_SCOPE_AGENT);   \
        while (v < (need_)) {                                       \
          __builtin_amdgcn_s_sleep(2);                              \
          v = (int)__hip_atomic_load(ptr_, __ATOMIC_RELAXED,        \
                                     __HIP_MEMORY_SCOPE_AGENT);     \
        }                                                           \
        (void)__hip_atomic_load(ptr_, __ATOMIC_ACQUIRE,             \
                                __HIP_MEMORY_SCOPE_AGENT);          \
        s_have = v;                                                 \
      }                                                             \
      __syncthreads();                                              \
      (have_) = s_have;                                             \
    }                                                               \
  } while (0)

  if (bid >= 48) {
    // ======================= producer roles ==============================
    const int gi = bid - 48;
    const int gl = gi >> 3;        // 0,1,2 : produces xg for layer gl
    const int bg = gi & 7;
    const int hw = wv & 7;         // row-wave within gate half
    const int j0 = (wv >> 3) * 2;  // gates {0,1} or {2,3}
    float* xgo = xg + (size_t)(gl * 8 + bg) * (XGRING_ * (size_t)XGSLOT_);
    unsigned int* fx_out = &flags[(64 + gl * 8 + bg) * FLAG_STRIDE_];
    unsigned int* fcp[4];
#pragma unroll
    for (int q = 0; q < 4; ++q)
      fcp[q] = &flags[(88 + gl * 32 + 4 * bg + q) * FLAG_STRIDE_];

    if (gl == 0) {
      // ---- layer-0 input GEMM: xg0 = bias0 + Wih0 . x (R19-proven math) ----
      f16x8 wih[2];
#pragma unroll
      for (int jj = 0; jj < 2; ++jj)
#pragma unroll
        for (int i = 0; i < 8; ++i) wih[jj][i] = (_Float16)0.f;
      if (quad == 0) {
#pragma unroll
        for (int jj = 0; jj < 2; ++jj) {
          const float* p = Wih0 + (size_t)((j0 + jj) * 128 + 16 * hw + n16) * IN_;
#pragma unroll
          for (int i = 0; i < IN_; ++i) wih[jj][i] = (_Float16)p[i];
        }
      }
      f32x4 bias4[2];
#pragma unroll
      for (int jj = 0; jj < 2; ++jj)
#pragma unroll
        for (int r = 0; r < 4; ++r) {
          int row = (j0 + jj) * 128 + 16 * hw + quad * 4 + r;
          bias4[jj][r] = bih0[row] + bhh0[row];
        }
      unsigned short* xbp = smem;                 // [32 t][16 b][8]
      int hc0 = 0, hc1 = 0, hc2 = 0, hc3 = 0;
      for (int k = 0; k < NCHUNK_; ++k) {
        if (k >= XGRING_) {
          WAITP(fcp[0], k - (XGRING_ - 1), hc0);
          WAITP(fcp[1], k - (XGRING_ - 1), hc1);
          WAITP(fcp[2], k - (XGRING_ - 1), hc2);
          WAITP(fcp[3], k - (XGRING_ - 1), hc3);
        }
        if (tid < 512) {
          const int tt = tid >> 4, bb = tid & 15;
          const float* xp = x + ((size_t)(bg * 16 + bb) * T_ + (size_t)(CHUNK_ * k + tt)) * IN_;
          uint4 v;
          v.x = pack2(xp[0], xp[1]); v.y = pack2(xp[2], xp[3]);
          v.z = pack2(xp[4], xp[5]); v.w = 0u;
          *(uint4*)&xbp[(tt * 16 + bb) * 8] = v;
        }
        __syncthreads();
        const int slot = k & 1;
        for (int t = 0; t < CHUNK_; ++t) {
          f16x8 xi;
#pragma unroll
          for (int i = 0; i < 8; ++i) xi[i] = (_Float16)0.f;
          if (quad == 0) xi = *(const f16x8*)&xbp[(t * 16 + n16) * 8];
          float* xp = xgo + (size_t)(slot * CHUNK_ + t) * 8192 + quad * 64 + n16 * 4;
#pragma unroll
          for (int jj = 0; jj < 2; ++jj) {
            f32x4 a = MFMA16(wih[jj], xi, bias4[jj]);
            *(f32x4*)(xp + (size_t)(8 * (j0 + jj) + hw) * 256) = a;
          }
        }
        __syncthreads();  // drains stores + protects LDS reuse
        if (tid == 0)
          __hip_atomic_store(fx_out, (unsigned int)(k + 1),
                             __ATOMIC_RELEASE, __HIP_MEMORY_SCOPE_AGENT);
      }
      return;
    }

    // ---- gl = 1,2 : hidden-state GEMM producers ----
    const int b8 = n16 & 7;
    const float* Wih = (gl == 1) ? Wih1 : Wih2;
    const float* bih = (gl == 1) ? bih1 : bih2;
    const float* bhh = (gl == 1) ? bhh1 : bhh2;
    unsigned int* fhp[4];
#pragma unroll
    for (int q = 0; q < 4; ++q)
      fhp[q] = &flags[((gl - 1) * 32 + 4 * bg + q) * FLAG_STRIDE_];

    f16x8 wih[2][4];
#pragma unroll
    for (int jj = 0; jj < 2; ++jj)
#pragma unroll
      for (int kc = 0; kc < 4; ++kc)
        wih[jj][kc] = load_w8(Wih + (size_t)((j0 + jj) * 128 + 16 * hw + n16) * H_
                              + kc * 32 + quad * 8);
    f32x4 bias4[2];
#pragma unroll
    for (int jj = 0; jj < 2; ++jj)
#pragma unroll
      for (int r = 0; r < 4; ++r) {
        int row = (j0 + jj) * 128 + 16 * hw + quad * 4 + r;
        bias4[jj][r] = bih[row] + bhh[row];
      }

    int hh0 = 0, hh1 = 0, hh2 = 0, hh3 = 0;
    int hc0 = 0, hc1 = 0, hc2 = 0, hc3 = 0;
    for (int k = 0; k < NCHUNK_; ++k) {
      WAITP(fhp[0], k + 1, hh0);
      WAITP(fhp[1], k + 1, hh1);
      WAITP(fhp[2], k + 1, hh2);
      WAITP(fhp[3], k + 1, hh3);
      if (k >= XGRING_) {
        WAITP(fcp[0], k - (XGRING_ - 1), hc0);
        WAITP(fcp[1], k - (XGRING_ - 1), hc1);
        WAITP(fcp[2], k - (XGRING_ - 1), hc2);
        WAITP(fcp[3], k - (XGRING_ - 1), hc3);
      }
      if (tid < 512) {
        const int tt = tid >> 4, bb = tid & 15;
        const int swk = bb & 7;
        const uint4* gp = (const uint4*)(region +
            ((size_t)(bg * 16 + bb) * T_ + (size_t)(CHUNK_ * k + tt)) * H_);
        uint4* lp = (uint4*)&smem[(tt * 16 + bb) * HS_];
#pragma unroll
        for (int i = 0; i < 16; ++i) lp[i ^ swk] = gp[i];
      }
      __syncthreads();
      const int slot = k & 1;
      for (int t = 0; t < CHUNK_; ++t) {
        f16x8 hi[4];
#pragma unroll
        for (int kc = 0; kc < 4; ++kc)
          hi[kc] = *(const f16x8*)&smem[(t * 16 + n16) * HS_ +
                                        ((kc * 32 + quad * 8) ^ (b8 << 3))];
        float* xp = xgo + (size_t)(slot * CHUNK_ + t) * 8192 + quad * 64 + n16 * 4;
#pragma unroll
        for (int jj = 0; jj < 2; ++jj) {
          f32x4 a = bias4[jj];
#pragma unroll
          for (int kc = 0; kc < 4; ++kc)
            a = MFMA16(wih[jj][kc], hi[kc], a);
          *(f32x4*)(xp + (size_t)(8 * (j0 + jj) + hw) * 256) = a;
        }
      }
      __syncthreads();  // drains stores + protects LDS reuse
      if (tid == 0)
        __hip_atomic_store(fx_out, (unsigned int)(k + 1),
                           __ATOMIC_RELEASE, __HIP_MEMORY_SCOPE_AGENT);
    }
    return;
  }

  // ========================= recurrence role =============================
  // 48 WGs: layer = bid>>4, pair = bid&15. chain = wv>>3 (two fused slices).
  const int layer = bid >> 4;
  const int pair  = bid & 15;
  const int chain = wv >> 3;           // 0/1
  const int cwv   = wv & 7;            // wave within chain (R16 wv)
  const int sl    = pair * 2 + chain;  // slice 0..31
  const int bcol  = n16 & 3;           // batch column (mirror-4)
  const int rr    = n16 >> 2;          // owned acc element
  const int batch = sl * 4 + bcol;
  const float* Whh = (layer == 0) ? Whh0 : ((layer == 1) ? Whh1 : Whh2);

  unsigned short* hstate = smem + chain * (2 * 4 * HS_);   // [2][4][HS_] per chain

  f16x8 whh[4][4];
#pragma unroll
  for (int j = 0; j < 4; ++j)
#pragma unroll
    for (int kc = 0; kc < 4; ++kc)
      whh[j][kc] = load_w8(Whh + (size_t)(j * 128 + 16 * cwv + n16) * H_ + kc * 32 + quad * 8);

  // zero both chains' hstate (2 x 1152 shorts = 1152 uints)
  for (int i = tid; i < 1152; i += 1024) ((unsigned int*)smem)[i] = 0u;

  float cc_ = 0.f;                     // single cell value per lane
  unsigned short dh16[GRP_];
  const bool r2 = (rr & 2) != 0, r1 = (rr & 1) != 0;
  const int hcol = 16 * cwv + 4 * quad + rr;        // h index this lane owns
  const int wswz = (((hcol >> 3) ^ bcol) << 3) | (hcol & 7);  // swizzled idx

  const int bg = sl >> 2;              // same for both fused chains
  const float* xgi = xg + (size_t)(layer * 8 + bg) * (XGRING_ * (size_t)XGSLOT_);
  const int xcol = (sl & 3) * 4 + bcol;
  f32x4 xr[2][4];
  auto load_xg = [&](int t, int buf) {
    int slot = (t >> 5) & 1;
    const float* p = xgi + (size_t)(slot * CHUNK_ + (t & 31)) * 8192
                     + (size_t)cwv * 256 + quad * 64 + xcol * 4;
    xr[buf][0] = *(const f32x4*)(p);
    xr[buf][1] = *(const f32x4*)(p + 2048);
    xr[buf][2] = *(const f32x4*)(p + 4096);
    xr[buf][3] = *(const f32x4*)(p + 6144);
  };
  unsigned int* fx_in  = &flags[(64 + layer * 8 + bg) * FLAG_STRIDE_];   // shared
  unsigned int* fc_out = &flags[(88 + layer * 32 + sl) * FLAG_STRIDE_];  // per chain
  unsigned int* fh_out = (layer < 2) ? &flags[(layer * 32 + sl) * FLAG_STRIDE_] : nullptr;
  int have_x = 0;
  __syncthreads();  // hstate zeros visible

#define SEL3(a_) (r1 ? (r2 ? (a_)[3] : (a_)[1]) : (r2 ? (a_)[2] : (a_)[0]))

  for (int g = 0; g < NGRP_; ++g) {
    if ((g & 3) == 0) {
      int c = g >> 2;
      WAITP(fx_in, c + 1, have_x);   // fx shared by both chains -> uniform
      load_xg(32 * c, 0);
      load_xg(32 * c + 1, 1);
    }
#pragma unroll
    for (int s = 0; s < GRP_; ++s) {
      const int t = 8 * g + s;
      const int rp = s & 1, wp = rp ^ 1;
      f16x8 hs[4];
#pragma unroll
      for (int kc = 0; kc < 4; ++kc)
        hs[kc] = *(const f16x8*)&hstate[(rp * 4 + bcol) * HS_ +
                                        ((kc * 32 + quad * 8) ^ (bcol << 3))];
      f32x4 ci[4];
#pragma unroll
      for (int j = 0; j < 4; ++j) ci[j] = xr[s & 1][j];
      if (!(((g & 3) == 3) && s >= 6)) load_xg(t + 2, s & 1);
      f32x4 acc[4];
#pragma unroll
      for (int j = 0; j < 4; ++j) {
        f32x4 aw = ci[j];
#pragma unroll
        for (int kc = 0; kc < 4; ++kc)
          aw = MFMA16(whh[j][kc], hs[kc], aw);
        acc[j] = aw;
      }
      float g4[4];
#pragma unroll
      for (int j = 0; j < 4; ++j) g4[j] = SEL3(acc[j]);
      float i_ = sigf_(g4[0]), f_ = sigf_(g4[1]), t_ = tanhf_(g4[2]), o_ = sigf_(g4[3]);
      cc_ = f_ * cc_ + i_ * t_;
      float h_ = o_ * tanhf_(cc_);
      unsigned short uh = f2h_u(h_);
      dh16[s] = uh;
      hstate[(wp * 4 + bcol) * HS_ + wswz] = uh;
      BARRIER_LGKM();
    }
    if (layer < 2) {
#pragma unroll
      for (int s = 0; s < GRP_; ++s)
        region[((size_t)batch * T_ + (8 * g + s)) * H_ + hcol] = dh16[s];
    }
    if ((g & 3) == 3) {
      PUBLISH_FENCE();   // all 16 waves drain vmcnt, then barrier
      if (lane == 0 && cwv == 0) {   // tid 0 (chain A) and tid 512 (chain B)
        unsigned int cdone = (unsigned int)((g >> 2) + 1);
        if (layer < 2)
          __hip_atomic_store(fh_out, cdone, __ATOMIC_RELEASE, __HIP_MEMORY_SCOPE_AGENT);
        __hip_atomic_store(fc_out, cdone, __ATOMIC_RELEASE, __HIP_MEMORY_SCOPE_AGENT);
      }
    }
  }
  if (layer == 2)
    ((unsigned short*)state_h)[(size_t)batch * 128 + hcol] = dh16[GRP_ - 1];
#undef SEL3
#undef WAITP
}

// ---------------------------------------------------------------------------
__global__ void head_kernel(const unsigned int* __restrict__ state_h,
                            const float* __restrict__ Wout,
                            const float* __restrict__ bout,
                            float* __restrict__ out)
{
  int b = threadIdx.x;  // 128 threads, 1 block
  float s = bout[0];
  for (int j = 0; j < 64; ++j) {
    unsigned int p = state_h[b * 64 + j];
    union { unsigned short u; _Float16 h; } lo, hi;
    lo.u = (unsigned short)(p & 0xffffu);
    hi.u = (unsigned short)(p >> 16);
    s += (float)lo.h * Wout[2 * j] + (float)hi.h * Wout[2 * j + 1];
  }
  out[b] = s;
}

// ---------------------------------------------------------------------------
extern "C" void kernel_launch(void* const* d_in, const int* in_sizes, int n_in,
                              void* d_out, int out_size, void* d_ws, size_t ws_size,
                              hipStream_t stream)
{
  const float* x = (const float*)d_in[0];
  const float* Wih[3] = {(const float*)d_in[1], (const float*)d_in[5], (const float*)d_in[9]};
  const float* Whh[3] = {(const float*)d_in[2], (const float*)d_in[6], (const float*)d_in[10]};
  const float* bih[3] = {(const float*)d_in[3], (const float*)d_in[7], (const float*)d_in[11]};
  const float* bhh[3] = {(const float*)d_in[4], (const float*)d_in[8], (const float*)d_in[12]};
  const float* Wout = (const float*)d_in[13];
  const float* bout = (const float*)d_in[14];
  float* out = (float*)d_out;

  char* ws = (char*)d_ws;
  size_t off = 0;
  unsigned short* region = (unsigned short*)(ws + off); off += (size_t)B_ * T_ * H_ * 2;            // 64 MiB
  float* xg = (float*)(ws + off);                       off += (size_t)24 * XGRING_ * XGSLOT_ * 4;  // 48 MiB
  unsigned int* state_h  = (unsigned int*)(ws + off);   off += (size_t)B_ * 64 * 4;
  off = (off + 255) & ~(size_t)255;
  unsigned int* flags    = (unsigned int*)(ws + off);   off += NFLAGS_ * FLAG_STRIDE_ * 4;

  init_flags<<<46, 256, 0, stream>>>(flags);
  lstm_pipe<<<72, 1024, 0, stream>>>(x,
      Wih[0], Whh[0], bih[0], bhh[0],
      Wih[1], Whh[1], bih[1], bhh[1],
      Wih[2], Whh[2], bih[2], bhh[2],
      region, xg, state_h, flags);
  head_kernel<<<1, 128, 0, stream>>>(state_h, Wout, bout, out);
}